// Round 1
// baseline (658.796 us; speedup 1.0000x reference)
//
#include <hip/hip_runtime.h>
#include <hip/hip_bf16.h>
#include <math.h>

#define BB 1024
#define PP 64
#define NN 512
#define EE 256

// per-batch output layout (floats): [feas 64 | workers 128 | known 4096 |
// unknown 4096 | differ 4096 | qa 64 | agg 256] = 12800
// float4 units: 16 | 32 | 1024 | 1024 | 1024 | 16 | 64 = 3200; copy part = 3136

#define LDA 264  // bf16 elems per LDS A-row (256 + 8 pad -> 2-way bank alias, free)

typedef short bf16x8 __attribute__((ext_vector_type(8)));
typedef float f32x4  __attribute__((ext_vector_type(4)));

__device__ inline unsigned short f2bf(float x) {
    union { float f; unsigned int u; } v; v.f = x;
    unsigned int r = (v.u + 0x7FFFu + ((v.u >> 16) & 1u)) >> 16;
    return (unsigned short)r;
}

// Repack W (E x E fp32, row-major, W[k][f]) into MFMA B-fragment order (bf16):
// for f-tile t (16 cols), k-chunk c (32 k), lane l: n = 16t+(l&15), k = 32c+(l>>4)*8+j
// flat dst = ((t*8+c)*64 + l)*8 + j  -> one contiguous 16B load per lane per frag.
__global__ void wconv_kernel(const float* __restrict__ W,
                             unsigned short* __restrict__ Wt) {
    int i = blockIdx.x * blockDim.x + threadIdx.x;  // 0..65535
    int k = i >> 8;
    int f = i & 255;
    int t = f >> 4;
    int c = k >> 5;
    int kk = k & 31;
    int lane = (kk >> 3) * 16 + (f & 15);
    int dst = (((t * 8 + c) * 64) + lane) * 8 + (kk & 7);
    Wt[dst] = f2bf(W[i]);
}

__global__ void fused_kernel(
    const float* __restrict__ feas, const float* __restrict__ workers,
    const float* __restrict__ known, const float* __restrict__ unknown,
    const float* __restrict__ differ, const float* __restrict__ qa,
    const int* __restrict__ pn, const float* __restrict__ embed,
    const float* __restrict__ bias, const unsigned short* __restrict__ Wt,
    float* __restrict__ out)
{
    if (blockIdx.x < BB) {
        // ---- GEMM block: one batch row ----
        __shared__ unsigned short sA[PP * LDA];
        const int b = blockIdx.x;
        const int tid = threadIdx.x;

        // gather 64 embed rows (fp32) -> bf16 LDS. 4 threads per row.
        {
            const int p = tid >> 2, q = tid & 3;
            const int idx = pn[b * PP + p];
            const float4* src =
                (const float4*)(embed + ((size_t)b * NN + idx) * EE) + q * 16;
            unsigned short* dst = sA + p * LDA + q * 64;
            #pragma unroll
            for (int i = 0; i < 16; ++i) {
                float4 v = src[i];
                dst[i * 4 + 0] = f2bf(v.x);
                dst[i * 4 + 1] = f2bf(v.y);
                dst[i * 4 + 2] = f2bf(v.z);
                dst[i * 4 + 3] = f2bf(v.w);
            }
        }
        __syncthreads();

        const int wave = tid >> 6, lane = tid & 63;
        const int m = lane & 15, quad = lane >> 4;

        f32x4 acc[4][4];  // [m-tile][f-tile]
        #pragma unroll
        for (int mt = 0; mt < 4; ++mt)
            #pragma unroll
            for (int ft = 0; ft < 4; ++ft)
                acc[mt][ft] = (f32x4){0.f, 0.f, 0.f, 0.f};

        #pragma unroll
        for (int c = 0; c < 8; ++c) {   // K = 256 = 8 chunks of 32
            bf16x8 aF[4], bF[4];
            #pragma unroll
            for (int mt = 0; mt < 4; ++mt) {
                const unsigned short* ap =
                    sA + (mt * 16 + m) * LDA + c * 32 + quad * 8;
                aF[mt] = *(const bf16x8*)ap;
            }
            #pragma unroll
            for (int ft = 0; ft < 4; ++ft) {
                const int t = wave * 4 + ft;
                const unsigned short* bp = Wt + (((t * 8 + c) * 64) + lane) * 8;
                bF[ft] = *(const bf16x8*)bp;
            }
            #pragma unroll
            for (int mt = 0; mt < 4; ++mt)
                #pragma unroll
                for (int ft = 0; ft < 4; ++ft)
                    acc[mt][ft] = __builtin_amdgcn_mfma_f32_16x16x32_bf16(
                        aF[mt], bF[ft], acc[mt][ft], 0, 0, 0);
        }

        // epilogue: tanh(C + bias), sum over all 64 p-rows, /64
        // C/D layout: col(f) = lane&15, row(p) = mt*16 + quad*4 + reg
        const float inv = 1.0f / 64.0f;
        #pragma unroll
        for (int ft = 0; ft < 4; ++ft) {
            const int f = wave * 64 + ft * 16 + m;
            const float bia = bias[f];
            float s = 0.f;
            #pragma unroll
            for (int mt = 0; mt < 4; ++mt)
                #pragma unroll
                for (int r = 0; r < 4; ++r)
                    s += tanhf(acc[mt][ft][r] + bia);
            s += __shfl_xor(s, 16, 64);
            s += __shfl_xor(s, 32, 64);
            if (quad == 0)
                out[(size_t)b * 12800 + 12544 + f] = s * inv;
        }
    } else {
        // ---- copy block: grid-stride float4 copy of the concat segments ----
        const int cid = blockIdx.x - BB;
        float4* out4 = (float4*)out;
        const float4* s_feas = (const float4*)feas;
        const float4* s_work = (const float4*)workers;
        const float4* s_know = (const float4*)known;
        const float4* s_unkn = (const float4*)unknown;
        const float4* s_diff = (const float4*)differ;
        const float4* s_qa   = (const float4*)qa;
        const int total = BB * 3136;
        for (int i = cid * 256 + threadIdx.x; i < total; i += BB * 256) {
            const int b = i / 3136;
            const int r = i - b * 3136;
            float4 v;
            if (r < 16)        v = s_feas[b * 16 + r];
            else if (r < 48)   v = s_work[b * 32 + (r - 16)];
            else if (r < 1072) v = s_know[(size_t)b * 1024 + (r - 48)];
            else if (r < 2096) v = s_unkn[(size_t)b * 1024 + (r - 1072)];
            else if (r < 3120) v = s_diff[(size_t)b * 1024 + (r - 2096)];
            else               v = s_qa[b * 16 + (r - 3120)];
            out4[(size_t)b * 3200 + r] = v;
        }
    }
}

extern "C" void kernel_launch(void* const* d_in, const int* in_sizes, int n_in,
                              void* d_out, int out_size, void* d_ws, size_t ws_size,
                              hipStream_t stream) {
    const float* feas    = (const float*)d_in[0];
    const float* workers = (const float*)d_in[1];
    const float* known   = (const float*)d_in[2];
    const float* unknown = (const float*)d_in[3];
    const float* differ  = (const float*)d_in[4];
    const float* qa      = (const float*)d_in[5];
    const int*   pn      = (const int*)d_in[6];
    const float* embed   = (const float*)d_in[7];
    const float* W       = (const float*)d_in[8];
    const float* bias    = (const float*)d_in[9];
    float* out = (float*)d_out;
    unsigned short* Wt = (unsigned short*)d_ws;  // 128 KB

    wconv_kernel<<<256, 256, 0, stream>>>(W, Wt);
    fused_kernel<<<2 * BB, 256, 0, stream>>>(feas, workers, known, unknown,
                                             differ, qa, pn, embed, bias, Wt,
                                             out);
}